// Round 3
// baseline (680.823 us; speedup 1.0000x reference)
//
#include <hip/hip_runtime.h>
#include <cstdint>

// Transformer decoder layer, MI355X gfx950. B=4 S=1024 D=1024 H=16 DH=64 FF=4096.
// Round 6: fragment-contiguous LDS layout for the GEMM ring (conflict-free
// ds_read_b128: each fragment read = 64 lanes x 16B contiguous). Staging
// source addresses pre-swizzled per lane (m173 / rule #21); LDS dest stays
// linear for global_load_lds. Ring/barrier/vmcnt structure unchanged from
// round 5 (623.1 us).

#define T_B 4
#define T_S 1024
#define T_D 1024
#define T_H 16
#define T_DH 64
#define T_FF 4096
#define T_TOK (T_B * T_S)

typedef __attribute__((ext_vector_type(8))) short bf16x8;
typedef __attribute__((ext_vector_type(4))) float f32x4;

__device__ __forceinline__ short f2bf(float f) {
  uint32_t u = __float_as_uint(f);
  u += 0x7FFFu + ((u >> 16) & 1u);  // round-to-nearest-even
  return (short)(u >> 16);
}

__device__ __forceinline__ float bf2f(short s) {
  return __uint_as_float(((uint32_t)(unsigned short)s) << 16);
}

// async global->LDS, 16B per lane. LDS dest = wave-uniform base + lane*16.
__device__ __forceinline__ void async_copy16(void* lds, const void* g) {
  __builtin_amdgcn_global_load_lds(
      (__attribute__((address_space(1))) uint32_t*)(uintptr_t)g,
      (__attribute__((address_space(3))) uint32_t*)(uint32_t)(uintptr_t)lds,
      16, 0, 0);
}

// Stage one 128x32 A-tile + 128x32 B-tile into ring slot `base`.
// Slot layout: 4 sections of 4096B: A rows 0-63, A rows 64-127, B rows 0-63,
// B rows 64-127. Within a section, fragment-contiguous order:
//   LDS[((grp*4 + kc)*16 + r)*16B] = elem[row = grp*16 + r][col = kc*8 ..+8]
// which global_load_lds produces from per-lane source row = w*16+(l&15),
// col-chunk = (l>>4)*8 (gA0/gB0 pointers encode this). 4 loads/thread.
__device__ __forceinline__ void stage_ring(char* base, const char* gA0,
                                           const char* gA1, const char* gB0,
                                           const char* gB1, int koffB, int wid) {
  async_copy16(base + (wid << 10), gA0 + koffB);
  async_copy16(base + 4096 + (wid << 10), gA1 + koffB);
  async_copy16(base + 8192 + (wid << 10), gB0 + koffB);
  async_copy16(base + 12288 + (wid << 10), gB1 + koffB);
}

// Fragment reads: av[mi] at slot + (wm>>6)*4096 + mi*1024 + lane*16 -> all 64
// lanes cover 1024 contiguous bytes = 8 full bank sweeps, conflict-free.
__device__ __forceinline__ void compute32(const char* slot, int aoff, int boff,
                                          f32x4 acc[4][4]) {
  bf16x8 av[4], bv[4];
#pragma unroll
  for (int i = 0; i < 4; ++i) {
    av[i] = *(const bf16x8*)(slot + aoff + (i << 10));
    bv[i] = *(const bf16x8*)(slot + 8192 + boff + (i << 10));
  }
#pragma unroll
  for (int mi = 0; mi < 4; ++mi)
#pragma unroll
    for (int ni = 0; ni < 4; ++ni)
      acc[mi][ni] = __builtin_amdgcn_mfma_f32_16x16x32_bf16(av[mi], bv[ni],
                                                            acc[mi][ni], 0, 0, 0);
}

// 128x128 tile mainloop: 3-buffer ring, BK=32 per iter, counted vmcnt.
// Correctness invariants (unchanged from round 5):
//  - stage(t+2) is issued after the barrier ending iter t-1, by which point
//    every wave's ds_reads of buf[(t+2)%3] are complete.
//  - vmcnt(4) at end of iter t leaves only stage(t+2)'s 4 loads outstanding,
//    so tile t+1 is fully landed before any wave crosses the barrier.
//  - tail iters (no further stage) use vmcnt(0).
// kLen must be a multiple of 64.
__device__ __forceinline__ void mfma_loop_ring(
    const short* __restrict__ A, int lda, const short* __restrict__ Bm, int ldb,
    int kLen, int m0, int n0, char* smem, f32x4 acc[4][4]) {
  const int t = threadIdx.x;
  const int lane = t & 63, wid = t >> 6;
  const int wm = (wid >> 1) << 6, wn = (wid & 1) << 6;
  // reader offsets (fragment-contiguous layout)
  const int aoff = ((wm >> 6) << 12) + (lane << 4);
  const int boff = ((wn >> 6) << 12) + (lane << 4);
  // staging source mapping: thread t covers row (t>>6)*16 + (t&15),
  // col chunk ((t>>4)&3)*8 of each 64-row section.
  const int srow = ((t >> 6) << 4) + (t & 15);
  const int scb = ((t >> 4) & 3) << 4;  // bytes
  const char* gA0 = (const char*)A + (((size_t)(m0 + srow) * lda) << 1) + scb;
  const char* gA1 = gA0 + ((size_t)lda << 7);  // +64 rows * 2B
  const char* gB0 = (const char*)Bm + (((size_t)(n0 + srow) * ldb) << 1) + scb;
  const char* gB1 = gB0 + ((size_t)ldb << 7);

  const f32x4 zf = {0.f, 0.f, 0.f, 0.f};
#pragma unroll
  for (int i = 0; i < 4; ++i)
#pragma unroll
    for (int j = 0; j < 4; ++j) acc[i][j] = zf;

  const int nIter = kLen >> 5;
  // prologue: stage tiles 0 and 1; wait tile 0 landed (4 of 8 outstanding).
  stage_ring(smem, gA0, gA1, gB0, gB1, 0, wid);
  stage_ring(smem + 16384, gA0, gA1, gB0, gB1, 64, wid);
  asm volatile("s_waitcnt vmcnt(4)" ::: "memory");
  __builtin_amdgcn_s_barrier();
  __builtin_amdgcn_sched_barrier(0);

  int cur = 0;
  for (int it = 0; it < nIter; ++it) {
    const int k2 = (it + 2) << 5;
    if (k2 < kLen) {
      int nb = cur + 2;
      if (nb >= 3) nb -= 3;
      stage_ring(smem + nb * 16384, gA0, gA1, gB0, gB1, k2 << 1, wid);
    }
    compute32(smem + cur * 16384, aoff, boff, acc);
    if (k2 < kLen)
      asm volatile("s_waitcnt vmcnt(4)" ::: "memory");
    else
      asm volatile("s_waitcnt vmcnt(0)" ::: "memory");
    __builtin_amdgcn_s_barrier();
    __builtin_amdgcn_sched_barrier(0);
    ++cur;
    if (cur >= 3) cur -= 3;
  }
}

// MODE 0: QKV fused (N=3072): q[b,h,s,dh], k[b,h,s,dh] direct; vt[b,h,dh,s]
//         staged via LDS for coalesced stores.
// MODE 2: relu bf16 out + bias (FF1)
template <int MODE>
__global__ __launch_bounds__(256) void gemm_dense(
    const short* __restrict__ A, const short* __restrict__ Bw, int K, int N,
    const float* __restrict__ bias0, const float* __restrict__ bias1,
    const float* __restrict__ bias2, short* __restrict__ outb0,
    short* __restrict__ outb1, short* __restrict__ outb2) {
  __shared__ __align__(16) char smem[49152];  // 3 ring buffers of 16 KiB
  const int m0 = blockIdx.x << 7, n0 = blockIdx.y << 7;
  f32x4 acc[4][4];
  mfma_loop_ring(A, K, Bw, K, K, m0, n0, smem, acc);

  const int t = threadIdx.x;
  const int lane = t & 63, wid = t >> 6;
  const int wm = (wid >> 1) << 6, wn = (wid & 1) << 6;
  const int quad = lane >> 4, r16 = lane & 15;

  if constexpr (MODE == 0) {
    const int which = n0 >> 10;  // block-uniform: 0=q 1=k 2=v
    const float* bias = (which == 0) ? bias0 : (which == 1) ? bias1 : bias2;
    if (which < 2) {
      short* outp = (which == 0) ? outb0 : outb1;
#pragma unroll
      for (int mi = 0; mi < 4; ++mi) {
#pragma unroll
        for (int ni = 0; ni < 4; ++ni) {
          const int col = n0 + wn + ni * 16 + r16;
          const int c10 = col & 1023;
          const float bb = bias[c10];
          const int hh = c10 >> 6, dh = col & 63;
#pragma unroll
          for (int reg = 0; reg < 4; ++reg) {
            const int row = m0 + wm + mi * 16 + quad * 4 + reg;
            const int b = row >> 10, s = row & 1023;
            outp[((((size_t)b * T_H + hh) * T_S) + s) * T_DH + dh] =
                f2bf(acc[mi][ni][reg] + bb);
          }
        }
      }
    } else {
      // V: stage [col][row] into padded LDS, then coalesced stores along s.
      __syncthreads();  // all waves done reading ring buffers
      short* vtile = (short*)smem;  // 128 x 136
#pragma unroll
      for (int mi = 0; mi < 4; ++mi)
#pragma unroll
        for (int ni = 0; ni < 4; ++ni) {
          const int c = wn + ni * 16 + r16;
          const float bb = bias[(n0 + c) & 1023];
#pragma unroll
          for (int reg = 0; reg < 4; ++reg) {
            const int r = wm + mi * 16 + quad * 4 + reg;
            vtile[c * 136 + r] = f2bf(acc[mi][ni][reg] + bb);
          }
        }
      __syncthreads();
      const int b = m0 >> 10, s0 = m0 & 1023;
      const int c = t >> 1, half = t & 1;
      const int c10 = (n0 + c) & 1023;
      const int hh = c10 >> 6, dh = c10 & 63;
      short* dst = outb2 + (((size_t)b * T_H + hh) * T_DH + dh) * T_S + s0 + half * 64;
      const short* srcl = vtile + c * 136 + half * 64;
#pragma unroll
      for (int j = 0; j < 8; ++j)
        *(bf16x8*)(dst + j * 8) = *(const bf16x8*)(srcl + j * 8);
    }
  } else {
#pragma unroll
    for (int mi = 0; mi < 4; ++mi)
#pragma unroll
      for (int ni = 0; ni < 4; ++ni) {
        const int col = n0 + wn + ni * 16 + r16;
        const float bb = bias0[col];
#pragma unroll
        for (int reg = 0; reg < 4; ++reg) {
          const int row = m0 + wm + mi * 16 + quad * 4 + reg;
          outb0[(size_t)row * N + col] = f2bf(fmaxf(acc[mi][ni][reg] + bb, 0.f));
        }
      }
  }
}

// split-K GEMM: partial f32, no bias. blockIdx.z = k-split index. kc % 64 == 0.
__global__ __launch_bounds__(256) void gemm_splitk(
    const short* __restrict__ A, const short* __restrict__ Bw, int K, int N,
    int kc, float* __restrict__ outp) {
  __shared__ __align__(16) char smem[49152];
  const int m0 = blockIdx.x << 7, n0 = blockIdx.y << 7, z = blockIdx.z;
  f32x4 acc[4][4];
  mfma_loop_ring(A + (size_t)z * kc, K, Bw + (size_t)z * kc, K, kc, m0, n0,
                 smem, acc);
  float* o = outp + (size_t)z * T_TOK * N;
  const int t = threadIdx.x;
  const int lane = t & 63, wid = t >> 6;
  const int wm = (wid >> 1) << 6, wn = (wid & 1) << 6;
  const int quad = lane >> 4, r16 = lane & 15;
#pragma unroll
  for (int mi = 0; mi < 4; ++mi)
#pragma unroll
    for (int ni = 0; ni < 4; ++ni) {
      const int col = n0 + wn + ni * 16 + r16;
#pragma unroll
      for (int reg = 0; reg < 4; ++reg) {
        const int row = m0 + wm + mi * 16 + quad * 4 + reg;
        o[(size_t)row * N + col] = acc[mi][ni][reg];
      }
    }
}

// Flash-style pass 1 (unchanged — verified).
__global__ __launch_bounds__(256) void attn_pass1(
    const short* __restrict__ qg, const short* __restrict__ kg,
    const short* __restrict__ vg, short* __restrict__ ctx,
    float* __restrict__ rsinv_g) {
  const int qb = blockIdx.x;
  const int bh = blockIdx.y;
  const int b = bh >> 4, h = bh & 15;
  const int m0 = qb << 7;
  __shared__ __align__(16) short Es[4 * 128 * 32];
  __shared__ float rsbuf[2][128];
  const int t = threadIdx.x;
  const int lane = t & 63, wid = t >> 6;
  const int quad = lane >> 4, r16 = lane & 15;
  const int wm = (wid >> 1) << 6, wn = (wid & 1) << 6;
  const int pvm = wid << 5;

  const short* Qbh = qg + (size_t)bh * T_S * T_DH;
  const short* Kbh = kg + (size_t)bh * T_S * T_DH;
  const short* Vbh = vg + (size_t)bh * T_DH * T_S;

  bf16x8 qf[4][2];
#pragma unroll
  for (int mi = 0; mi < 4; ++mi)
#pragma unroll
    for (int ksd = 0; ksd < 2; ++ksd)
      qf[mi][ksd] = *(const bf16x8*)(Qbh + (size_t)(m0 + wm + mi * 16 + r16) * T_DH +
                                     ksd * 32 + quad * 8);

  float rs[4][4];
#pragma unroll
  for (int i = 0; i < 4; ++i)
#pragma unroll
    for (int j = 0; j < 4; ++j) rs[i][j] = 0.f;
  const f32x4 zf = {0.f, 0.f, 0.f, 0.f};
  f32x4 accp[2][4];
#pragma unroll
  for (int i = 0; i < 2; ++i)
#pragma unroll
    for (int j = 0; j < 4; ++j) accp[i][j] = zf;

  for (int kt = 0; kt <= qb; ++kt) {
    f32x4 accs[4][4];
#pragma unroll
    for (int i = 0; i < 4; ++i)
#pragma unroll
      for (int j = 0; j < 4; ++j) accs[i][j] = zf;
#pragma unroll
    for (int ksd = 0; ksd < 2; ++ksd) {
      bf16x8 bv[4];
#pragma unroll
      for (int ni = 0; ni < 4; ++ni)
        bv[ni] = *(const bf16x8*)(Kbh + (size_t)(kt * 128 + wn + ni * 16 + r16) * T_DH +
                                  ksd * 32 + quad * 8);
#pragma unroll
      for (int mi = 0; mi < 4; ++mi)
#pragma unroll
        for (int ni = 0; ni < 4; ++ni)
          accs[mi][ni] = __builtin_amdgcn_mfma_f32_16x16x32_bf16(
              qf[mi][ksd], bv[ni], accs[mi][ni], 0, 0, 0);
    }
    __syncthreads();
    const bool diag = (kt == qb);
#pragma unroll
    for (int mi = 0; mi < 4; ++mi) {
#pragma unroll
      for (int ni = 0; ni < 4; ++ni) {
        const int cbase = wn + ni * 16;
        const int kse = cbase >> 5;
        const int sin = (cbase & 31) + r16;
        short* ep = Es + kse * 4096 + (wm + mi * 16 + quad * 4) * 32 + sin;
        const int colw = cbase + r16;
#pragma unroll
        for (int reg = 0; reg < 4; ++reg) {
          float e = __expf(accs[mi][ni][reg] * 0.125f);
          if (diag && colw > (wm + mi * 16 + quad * 4 + reg)) e = 0.f;
          ep[reg * 32] = f2bf(e);
          rs[mi][reg] += e;
        }
      }
    }
    __syncthreads();
#pragma unroll
    for (int ks = 0; ks < 4; ++ks) {
      bf16x8 av[2], bvv[4];
#pragma unroll
      for (int i = 0; i < 2; ++i)
        av[i] = *(const bf16x8*)(Es + ks * 4096 + (pvm + i * 16 + r16) * 32 + quad * 8);
#pragma unroll
      for (int ni = 0; ni < 4; ++ni)
        bvv[ni] = *(const bf16x8*)(Vbh + (size_t)(ni * 16 + r16) * T_S + kt * 128 +
                                   ks * 32 + quad * 8);
#pragma unroll
      for (int i = 0; i < 2; ++i)
#pragma unroll
        for (int ni = 0; ni < 4; ++ni)
          accp[i][ni] = __builtin_amdgcn_mfma_f32_16x16x32_bf16(av[i], bvv[ni],
                                                                accp[i][ni], 0, 0, 0);
    }
  }

#pragma unroll
  for (int mi = 0; mi < 4; ++mi)
#pragma unroll
    for (int reg = 0; reg < 4; ++reg) {
#pragma unroll
      for (int d = 1; d < 16; d <<= 1)
        rs[mi][reg] += __shfl_xor(rs[mi][reg], d, 64);
    }
  if (r16 == 0) {
#pragma unroll
    for (int mi = 0; mi < 4; ++mi)
#pragma unroll
      for (int reg = 0; reg < 4; ++reg)
        rsbuf[wid & 1][wm + mi * 16 + quad * 4 + reg] = rs[mi][reg];
  }
  __syncthreads();
  if (t < 128) {
    const float iv = 1.f / (rsbuf[0][t] + rsbuf[1][t]);
    rsbuf[0][t] = iv;
    rsinv_g[(size_t)bh * T_S + m0 + t] = iv;
  }
  __syncthreads();
#pragma unroll
  for (int i = 0; i < 2; ++i)
#pragma unroll
    for (int ni = 0; ni < 4; ++ni) {
#pragma unroll
      for (int reg = 0; reg < 4; ++reg) {
        const int row = pvm + i * 16 + quad * 4 + reg;
        const float iv = rsbuf[0][row];
        ctx[((size_t)b * T_S + m0 + row) * T_D + h * 64 + ni * 16 + r16] =
            f2bf(accp[i][ni][reg] * iv);
      }
    }
}

// Pass 2 (unchanged): write attn; masked tiles zero; else recompute scores.
__global__ __launch_bounds__(256) void attn_pass2(
    const short* __restrict__ qg, const short* __restrict__ kg,
    const float* __restrict__ rsinv_g, float* __restrict__ attn) {
  const int qb = blockIdx.x, kt = blockIdx.y, bh = blockIdx.z;
  float* out = attn + ((size_t)bh * T_S + qb * 128) * T_S + kt * 128;
  const int t = threadIdx.x;
  if (kt > qb) {
    const float4 z4 = {0.f, 0.f, 0.f, 0.f};
#pragma unroll
    for (int j = 0; j < 16; ++j) {
      const int id = t + j * 256;
      ((float4*)(out + (size_t)(id >> 5) * T_S))[id & 31] = z4;
    }
    return;
  }
  const int lane = t & 63, wid = t >> 6;
  const int quad = lane >> 4, r16 = lane & 15;
  const int wm = (wid >> 1) << 6, wn = (wid & 1) << 6;
  const short* Qbh = qg + (size_t)bh * T_S * T_DH;
  const short* Kbh = kg + (size_t)bh * T_S * T_DH;
  const f32x4 zf = {0.f, 0.f, 0.f, 0.f};
  f32x4 accs[4][4];
#pragma unroll
  for (int i = 0; i < 4; ++i)
#pragma unroll
    for (int j = 0; j < 4; ++j) accs[i][j] = zf;
#pragma unroll
  for (int ksd = 0; ksd < 2; ++ksd) {
    bf16x8 aq[4], bv[4];
#pragma unroll
    for (int mi = 0; mi < 4; ++mi)
      aq[mi] = *(const bf16x8*)(Qbh + (size_t)(qb * 128 + wm + mi * 16 + r16) * T_DH +
                                ksd * 32 + quad * 8);
#pragma unroll
    for (int ni = 0; ni < 4; ++ni)
      bv[ni] = *(const bf16x8*)(Kbh + (size_t)(kt * 128 + wn + ni * 16 + r16) * T_DH +
                                ksd * 32 + quad * 8);
#pragma unroll
    for (int mi = 0; mi < 4; ++mi)
#pragma unroll
      for (int ni = 0; ni < 4; ++ni)
        accs[mi][ni] = __builtin_amdgcn_mfma_f32_16x16x32_bf16(aq[mi], bv[ni],
                                                               accs[mi][ni], 0, 0, 0);
  }
  const bool diag = (kt == qb);
#pragma unroll
  for (int mi = 0; mi < 4; ++mi)
#pragma unroll
    for (int ni = 0; ni < 4; ++ni) {
      const int col = wn + ni * 16 + r16;
#pragma unroll
      for (int reg = 0; reg < 4; ++reg) {
        const int rowt = wm + mi * 16 + quad * 4 + reg;
        const float iv = rsinv_g[(size_t)bh * T_S + qb * 128 + rowt];
        float e = __expf(accs[mi][ni][reg] * 0.125f) * iv;
        if (diag && col > rowt) e = 0.f;
        out[(size_t)rowt * T_S + col] = e;
      }
    }
}

// LayerNorm(a + sum(parts) + biasvec) * g + be. Residual a from f32 or bf16.
__global__ __launch_bounds__(256) void ln_multi(
    const float* __restrict__ a32, const short* __restrict__ a16,
    const float* __restrict__ parts, int nparts, const float* __restrict__ bias,
    const float* __restrict__ g, const float* __restrict__ be,
    float* __restrict__ outf, short* __restrict__ outb) {
  const int row = blockIdx.x;
  const int t = threadIdx.x;
  float4 x;
  if (a32 != nullptr) {
    x = ((const float4*)(a32 + (size_t)row * T_D))[t];
  } else {
    const short4 s4 = ((const short4*)(a16 + (size_t)row * T_D))[t];
    x.x = bf2f(s4.x); x.y = bf2f(s4.y); x.z = bf2f(s4.z); x.w = bf2f(s4.w);
  }
  const float4 bv = ((const float4*)bias)[t];
  x.x += bv.x; x.y += bv.y; x.z += bv.z; x.w += bv.w;
  for (int p = 0; p < nparts; ++p) {
    const float4 v =
        ((const float4*)(parts + (size_t)p * T_TOK * T_D + (size_t)row * T_D))[t];
    x.x += v.x; x.y += v.y; x.z += v.z; x.w += v.w;
  }
  float sum = x.x + x.y + x.z + x.w;
  float sq = x.x * x.x + x.y * x.y + x.z * x.z + x.w * x.w;
  __shared__ float reds[4], redq[4];
  const int lane = t & 63, wid = t >> 6;
#pragma unroll
  for (int o = 32; o > 0; o >>= 1) {
    sum += __shfl_down(sum, o, 64);
    sq += __shfl_down(sq, o, 64);
  }
  if (lane == 0) { reds[wid] = sum; redq[wid] = sq; }
  __syncthreads();
  sum = reds[0] + reds[1] + reds[2] + reds[3];
  sq = redq[0] + redq[1] + redq[2] + redq[3];
  const float mean = sum * (1.f / T_D);
  const float var = sq * (1.f / T_D) - mean * mean;
  const float rstd = rsqrtf(var + 1e-5f);
  const float4 gg = ((const float4*)g)[t];
  const float4 bb = ((const float4*)be)[t];
  float4 y;
  y.x = (x.x - mean) * rstd * gg.x + bb.x;
  y.y = (x.y - mean) * rstd * gg.y + bb.y;
  y.z = (x.z - mean) * rstd * gg.z + bb.z;
  y.w = (x.w - mean) * rstd * gg.w + bb.w;
  if (outf != nullptr) ((float4*)(outf + (size_t)row * T_D))[t] = y;
  if (outb != nullptr) {
    short4 o4;
    o4.x = f2bf(y.x); o4.y = f2bf(y.y); o4.z = f2bf(y.z); o4.w = f2bf(y.w);
    ((short4*)(outb + (size_t)row * T_D))[t] = o4;
  }
}

// Fused prep: x->bf16 (blocks 0..4095) + five weight transposes (f32->bf16^T).
__global__ __launch_bounds__(256) void prep_kernel(
    const float* __restrict__ x, short* __restrict__ xb,
    const float* __restrict__ Wq, const float* __restrict__ Wk,
    const float* __restrict__ Wv, const float* __restrict__ Wo,
    const float* __restrict__ W1, const float* __restrict__ W2,
    short* __restrict__ Wqkv_t, short* __restrict__ Wo_t,
    short* __restrict__ W1_t, short* __restrict__ W2_t) {
  int id = blockIdx.x;
  const int t = threadIdx.x;
  if (id < 4096) {
    const int i = id * 256 + t;
    const float4 v = ((const float4*)x)[i];
    short4 o;
    o.x = f2bf(v.x); o.y = f2bf(v.y); o.z = f2bf(v.z); o.w = f2bf(v.w);
    ((short4*)xb)[i] = o;
    return;
  }
  id -= 4096;
  const float* src;
  short* dst;
  int R, C;  // src[R][C] -> dst[C][R]
  if (id < 1024) { src = Wq; dst = Wqkv_t; R = 1024; C = 1024; }
  else if (id < 2048) { id -= 1024; src = Wk; dst = Wqkv_t + 1024 * 1024; R = 1024; C = 1024; }
  else if (id < 3072) { id -= 2048; src = Wv; dst = Wqkv_t + 2 * 1024 * 1024; R = 1024; C = 1024; }
  else if (id < 4096) { id -= 3072; src = Wo; dst = Wo_t; R = 1024; C = 1024; }
  else if (id < 8192) { id -= 4096; src = W1; dst = W1_t; R = 1024; C = 4096; }
  else { id -= 8192; src = W2; dst = W2_t; R = 4096; C = 1024; }
  const int tilesC = C >> 5;
  const int r0 = (id / tilesC) << 5, c0 = (id % tilesC) << 5;
  __shared__ float tile[32][33];
  const int tx = t & 31, ty = t >> 5;  // 32 x 8
#pragma unroll
  for (int j = 0; j < 4; ++j)
    tile[ty + j * 8][tx] = src[(size_t)(r0 + ty + j * 8) * C + c0 + tx];
  __syncthreads();
#pragma unroll
  for (int j = 0; j < 4; ++j)
    dst[(size_t)(c0 + ty + j * 8) * R + r0 + tx] = f2bf(tile[tx][ty + j * 8]);
}

extern "C" void kernel_launch(void* const* d_in, const int* in_sizes, int n_in,
                              void* d_out, int out_size, void* d_ws,
                              size_t ws_size, hipStream_t stream) {
  const float* x = (const float*)d_in[0];
  const float* Wq = (const float*)d_in[1];
  const float* bq = (const float*)d_in[2];
  const float* Wk = (const float*)d_in[3];
  const float* bk = (const float*)d_in[4];
  const float* Wv = (const float*)d_in[5];
  const float* bv = (const float*)d_in[6];
  const float* Wo = (const float*)d_in[7];
  const float* bo = (const float*)d_in[8];
  const float* ln1g = (const float*)d_in[9];
  const float* ln1b = (const float*)d_in[10];
  const float* W1 = (const float*)d_in[11];
  const float* b1 = (const float*)d_in[12];
  const float* W2 = (const float*)d_in[13];
  const float* b2 = (const float*)d_in[14];
  const float* ln2g = (const float*)d_in[15];
  const float* ln2b = (const float*)d_in[16];
  (void)in_sizes; (void)n_in; (void)out_size; (void)ws_size;

  float* y_out = (float*)d_out;
  float* attn = (float*)d_out + (size_t)T_TOK * T_D;

  char* w = (char*)d_ws;
  size_t off = 0;
  auto alloc = [&](size_t bytes) -> void* {
    void* p = w + off;
    off += (bytes + 255) & ~(size_t)255;
    return p;
  };
  short* xb     = (short*)alloc((size_t)T_TOK * T_D * 2);
  short* Wqkv_t = (short*)alloc((size_t)3 * T_D * T_D * 2);
  short* Wo_t   = (short*)alloc((size_t)T_D * T_D * 2);
  short* W1_t   = (short*)alloc((size_t)T_FF * T_D * 2);
  short* W2_t   = (short*)alloc((size_t)T_D * T_FF * 2);
  short* qb_    = (short*)alloc((size_t)T_TOK * T_D * 2);
  short* kb_    = (short*)alloc((size_t)T_TOK * T_D * 2);
  short* vtb    = (short*)alloc((size_t)T_TOK * T_D * 2);
  short* ctx    = (short*)alloc((size_t)T_TOK * T_D * 2);
  short* hb     = (short*)alloc((size_t)T_TOK * T_D * 2);
  short* ff1    = (short*)alloc((size_t)T_TOK * T_FF * 2);
  float* rsinv  = (float*)alloc((size_t)T_H * T_B * T_S * 4);
  float* woP    = (float*)alloc((size_t)2 * T_TOK * T_D * 4);
  float* ffP    = (float*)alloc((size_t)2 * T_TOK * T_D * 4);

  prep_kernel<<<dim3(16384), dim3(256), 0, stream>>>(
      x, xb, Wq, Wk, Wv, Wo, W1, W2, Wqkv_t, Wo_t, W1_t, W2_t);

  gemm_dense<0><<<dim3(32, 24), dim3(256), 0, stream>>>(
      xb, Wqkv_t, T_D, 3072, bq, bk, bv, qb_, kb_, vtb);
  attn_pass1<<<dim3(8, 64), dim3(256), 0, stream>>>(qb_, kb_, vtb, ctx, rsinv);
  attn_pass2<<<dim3(8, 8, 64), dim3(256), 0, stream>>>(qb_, kb_, rsinv, attn);

  gemm_splitk<<<dim3(32, 8, 2), dim3(256), 0, stream>>>(ctx, Wo_t, T_D, T_D, 512, woP);
  ln_multi<<<dim3(4096), dim3(256), 0, stream>>>(x, nullptr, woP, 2, bo, ln1g,
                                                 ln1b, nullptr, hb);

  gemm_dense<2><<<dim3(32, 32), dim3(256), 0, stream>>>(
      hb, W1_t, T_D, T_FF, b1, nullptr, nullptr, ff1, nullptr, nullptr);
  gemm_splitk<<<dim3(32, 8, 2), dim3(256), 0, stream>>>(ff1, W2_t, T_FF, T_D, 2048, ffP);
  ln_multi<<<dim3(4096), dim3(256), 0, stream>>>(nullptr, hb, ffP, 2, b2, ln2g,
                                                 ln2b, y_out, nullptr);
}

// Round 4
// 616.753 us; speedup vs baseline: 1.1039x; 1.1039x over previous
//
#include <hip/hip_runtime.h>
#include <cstdint>

// Transformer decoder layer, MI355X gfx950. B=4 S=1024 D=1024 H=16 DH=64 FF=4096.
// Round 7: revert round-6's A-side experiment (regressed: lane-scattered
// staging broke VMEM coalescing). Keep round-5 ring mainloop (623.1 us).
// NEW: weights pre-PACKED by prep_kernel into fragment-contiguous order
// [n-panel 128][k-tile 32][n-half 64][g 0..3][kc 0..3][r 0..15] x 8 shorts,
// so B staging reads 1024 CONTIGUOUS bytes per wave-load (perfect
// coalescing) and B ds_read_b128 fragments are 64-lane contiguous
// (conflict-free by construction). A-side staging/reads unchanged (proven).

#define T_B 4
#define T_S 1024
#define T_D 1024
#define T_H 16
#define T_DH 64
#define T_FF 4096
#define T_TOK (T_B * T_S)

typedef __attribute__((ext_vector_type(8))) short bf16x8;
typedef __attribute__((ext_vector_type(4))) float f32x4;

__device__ __forceinline__ short f2bf(float f) {
  uint32_t u = __float_as_uint(f);
  u += 0x7FFFu + ((u >> 16) & 1u);  // round-to-nearest-even
  return (short)(u >> 16);
}

__device__ __forceinline__ float bf2f(short s) {
  return __uint_as_float(((uint32_t)(unsigned short)s) << 16);
}

// async global->LDS, 16B per lane. LDS dest = wave-uniform base + lane*16.
__device__ __forceinline__ void async_copy16(void* lds, const void* g) {
  __builtin_amdgcn_global_load_lds(
      (__attribute__((address_space(1))) uint32_t*)(uintptr_t)g,
      (__attribute__((address_space(3))) uint32_t*)(uint32_t)(uintptr_t)lds,
      16, 0, 0);
}

// Stage one 128x32 A-tile (row-major source, 16x64B runs) + one 128x32
// packed-B tile (two 4096B contiguous sections) into ring slot `base`.
// Slot: A rows 0-63 at +0, A rows 64-127 at +4096, B n0-63 at +8192,
// B n64-127 at +12288. 4 loads/thread.
__device__ __forceinline__ void stage_ring(char* base, const char* gA0,
                                           const char* gA1, const char* gB0,
                                           const char* gB1, int koffA, int koffB,
                                           int wid) {
  async_copy16(base + (wid << 10), gA0 + koffA);
  async_copy16(base + 4096 + (wid << 10), gA1 + koffA);
  async_copy16(base + 8192 + (wid << 10), gB0 + koffB);
  async_copy16(base + 12288 + (wid << 10), gB1 + koffB);
}

// A fragments: proven row-major reads. B fragments: packed layout ->
// slot + 8192 + (wn>>6)*4096 + i*1024 + lane*16 (64 lanes x 16B contiguous).
__device__ __forceinline__ void compute32(const char* slot, int wm, int quad,
                                          int r16, int boffB, f32x4 acc[4][4]) {
  const short* As = (const short*)slot;
  bf16x8 av[4], bv[4];
#pragma unroll
  for (int i = 0; i < 4; ++i) {
    av[i] = *(const bf16x8*)(As + ((wm + i * 16 + r16) << 5) + (quad << 3));
    bv[i] = *(const bf16x8*)(slot + 8192 + boffB + (i << 10));
  }
#pragma unroll
  for (int mi = 0; mi < 4; ++mi)
#pragma unroll
    for (int ni = 0; ni < 4; ++ni)
      acc[mi][ni] = __builtin_amdgcn_mfma_f32_16x16x32_bf16(av[mi], bv[ni],
                                                            acc[mi][ni], 0, 0, 0);
}

// 128x128 tile mainloop: 3-buffer ring, BK=32 per iter, counted vmcnt.
// Invariants (proven rounds 4-5):
//  - stage(t+2) issued after the barrier ending iter t-1 (its buffer's
//    readers are done).
//  - vmcnt(4) at end of iter t -> tile t+1 fully landed before the barrier.
//  - tail iters use vmcnt(0).
// A: row-major [M][lda], k-window [0,kLen) (caller pre-offsets for splitk).
// Bpack: packed weights, full-K = ldbK, k-window [kBase, kBase+kLen).
__device__ __forceinline__ void mfma_loop_ring(
    const short* __restrict__ A, int lda, const char* __restrict__ Bpack,
    int ldbK, int kBase, int kLen, int m0, int n0, char* smem,
    f32x4 acc[4][4]) {
  const int t = threadIdx.x;
  const int lane = t & 63, wid = t >> 6;
  const int wm = (wid >> 1) << 6, wn = (wid & 1) << 6;
  const int quad = lane >> 4, r16 = lane & 15;
  const int boffB = ((wn >> 6) << 12) + (lane << 4);
  const int row0 = t >> 2, cb0 = (t & 3) << 4;
  const char* gA0 = (const char*)A + (((size_t)(m0 + row0) * lda) << 1) + cb0;
  const char* gA1 = gA0 + ((size_t)lda << 7);  // +64 rows * 2B
  const char* gB0 = Bpack +
      ((size_t)(n0 >> 7) * (ldbK >> 5) + (kBase >> 5)) * 8192 + (t << 4);
  const char* gB1 = gB0 + 4096;

  const f32x4 zf = {0.f, 0.f, 0.f, 0.f};
#pragma unroll
  for (int i = 0; i < 4; ++i)
#pragma unroll
    for (int j = 0; j < 4; ++j) acc[i][j] = zf;

  const int nIter = kLen >> 5;
  // prologue: stage tiles 0 and 1; wait tile 0 landed (4 of 8 outstanding).
  stage_ring(smem, gA0, gA1, gB0, gB1, 0, 0, wid);
  stage_ring(smem + 16384, gA0, gA1, gB0, gB1, 64, 8192, wid);
  asm volatile("s_waitcnt vmcnt(4)" ::: "memory");
  __builtin_amdgcn_s_barrier();
  __builtin_amdgcn_sched_barrier(0);

  int cur = 0;
  for (int it = 0; it < nIter; ++it) {
    const int k2 = (it + 2) << 5;
    if (k2 < kLen) {
      int nb = cur + 2;
      if (nb >= 3) nb -= 3;
      stage_ring(smem + nb * 16384, gA0, gA1, gB0, gB1, k2 << 1, k2 << 8, wid);
    }
    compute32(smem + cur * 16384, wm, quad, r16, boffB, acc);
    if (k2 < kLen)
      asm volatile("s_waitcnt vmcnt(4)" ::: "memory");
    else
      asm volatile("s_waitcnt vmcnt(0)" ::: "memory");
    __builtin_amdgcn_s_barrier();
    __builtin_amdgcn_sched_barrier(0);
    ++cur;
    if (cur >= 3) cur -= 3;
  }
}

// MODE 0: QKV fused (N=3072): q[b,h,s,dh], k[b,h,s,dh] direct; vt[b,h,dh,s]
//         staged via LDS for coalesced stores.
// MODE 2: relu bf16 out + bias (FF1)
template <int MODE>
__global__ __launch_bounds__(256) void gemm_dense(
    const short* __restrict__ A, const short* __restrict__ Bw, int K, int N,
    const float* __restrict__ bias0, const float* __restrict__ bias1,
    const float* __restrict__ bias2, short* __restrict__ outb0,
    short* __restrict__ outb1, short* __restrict__ outb2) {
  __shared__ __align__(16) char smem[49152];  // 3 ring buffers of 16 KiB
  const int m0 = blockIdx.x << 7, n0 = blockIdx.y << 7;
  f32x4 acc[4][4];
  mfma_loop_ring(A, K, (const char*)Bw, K, 0, K, m0, n0, smem, acc);

  const int t = threadIdx.x;
  const int lane = t & 63, wid = t >> 6;
  const int wm = (wid >> 1) << 6, wn = (wid & 1) << 6;
  const int quad = lane >> 4, r16 = lane & 15;

  if constexpr (MODE == 0) {
    const int which = n0 >> 10;  // block-uniform: 0=q 1=k 2=v
    const float* bias = (which == 0) ? bias0 : (which == 1) ? bias1 : bias2;
    if (which < 2) {
      short* outp = (which == 0) ? outb0 : outb1;
#pragma unroll
      for (int mi = 0; mi < 4; ++mi) {
#pragma unroll
        for (int ni = 0; ni < 4; ++ni) {
          const int col = n0 + wn + ni * 16 + r16;
          const int c10 = col & 1023;
          const float bb = bias[c10];
          const int hh = c10 >> 6, dh = col & 63;
#pragma unroll
          for (int reg = 0; reg < 4; ++reg) {
            const int row = m0 + wm + mi * 16 + quad * 4 + reg;
            const int b = row >> 10, s = row & 1023;
            outp[((((size_t)b * T_H + hh) * T_S) + s) * T_DH + dh] =
                f2bf(acc[mi][ni][reg] + bb);
          }
        }
      }
    } else {
      // V: stage [col][row] into padded LDS, then coalesced stores along s.
      __syncthreads();  // all waves done reading ring buffers
      short* vtile = (short*)smem;  // 128 x 136
#pragma unroll
      for (int mi = 0; mi < 4; ++mi)
#pragma unroll
        for (int ni = 0; ni < 4; ++ni) {
          const int c = wn + ni * 16 + r16;
          const float bb = bias[(n0 + c) & 1023];
#pragma unroll
          for (int reg = 0; reg < 4; ++reg) {
            const int r = wm + mi * 16 + quad * 4 + reg;
            vtile[c * 136 + r] = f2bf(acc[mi][ni][reg] + bb);
          }
        }
      __syncthreads();
      const int b = m0 >> 10, s0 = m0 & 1023;
      const int c = t >> 1, half = t & 1;
      const int c10 = (n0 + c) & 1023;
      const int hh = c10 >> 6, dh = c10 & 63;
      short* dst = outb2 + (((size_t)b * T_H + hh) * T_DH + dh) * T_S + s0 + half * 64;
      const short* srcl = vtile + c * 136 + half * 64;
#pragma unroll
      for (int j = 0; j < 8; ++j)
        *(bf16x8*)(dst + j * 8) = *(const bf16x8*)(srcl + j * 8);
    }
  } else {
#pragma unroll
    for (int mi = 0; mi < 4; ++mi)
#pragma unroll
      for (int ni = 0; ni < 4; ++ni) {
        const int col = n0 + wn + ni * 16 + r16;
        const float bb = bias0[col];
#pragma unroll
        for (int reg = 0; reg < 4; ++reg) {
          const int row = m0 + wm + mi * 16 + quad * 4 + reg;
          outb0[(size_t)row * N + col] = f2bf(fmaxf(acc[mi][ni][reg] + bb, 0.f));
        }
      }
  }
}

// split-K GEMM: partial f32, no bias. blockIdx.z = k-split index. kc % 64 == 0.
__global__ __launch_bounds__(256) void gemm_splitk(
    const short* __restrict__ A, const short* __restrict__ Bw, int K, int N,
    int kc, float* __restrict__ outp) {
  __shared__ __align__(16) char smem[49152];
  const int m0 = blockIdx.x << 7, n0 = blockIdx.y << 7, z = blockIdx.z;
  f32x4 acc[4][4];
  mfma_loop_ring(A + (size_t)z * kc, K, (const char*)Bw, K, z * kc, kc, m0, n0,
                 smem, acc);
  float* o = outp + (size_t)z * T_TOK * N;
  const int t = threadIdx.x;
  const int lane = t & 63, wid = t >> 6;
  const int wm = (wid >> 1) << 6, wn = (wid & 1) << 6;
  const int quad = lane >> 4, r16 = lane & 15;
#pragma unroll
  for (int mi = 0; mi < 4; ++mi)
#pragma unroll
    for (int ni = 0; ni < 4; ++ni) {
      const int col = n0 + wn + ni * 16 + r16;
#pragma unroll
      for (int reg = 0; reg < 4; ++reg) {
        const int row = m0 + wm + mi * 16 + quad * 4 + reg;
        o[(size_t)row * N + col] = acc[mi][ni][reg];
      }
    }
}

// Flash-style pass 1 (unchanged — verified).
__global__ __launch_bounds__(256) void attn_pass1(
    const short* __restrict__ qg, const short* __restrict__ kg,
    const short* __restrict__ vg, short* __restrict__ ctx,
    float* __restrict__ rsinv_g) {
  const int qb = blockIdx.x;
  const int bh = blockIdx.y;
  const int b = bh >> 4, h = bh & 15;
  const int m0 = qb << 7;
  __shared__ __align__(16) short Es[4 * 128 * 32];
  __shared__ float rsbuf[2][128];
  const int t = threadIdx.x;
  const int lane = t & 63, wid = t >> 6;
  const int quad = lane >> 4, r16 = lane & 15;
  const int wm = (wid >> 1) << 6, wn = (wid & 1) << 6;
  const int pvm = wid << 5;

  const short* Qbh = qg + (size_t)bh * T_S * T_DH;
  const short* Kbh = kg + (size_t)bh * T_S * T_DH;
  const short* Vbh = vg + (size_t)bh * T_DH * T_S;

  bf16x8 qf[4][2];
#pragma unroll
  for (int mi = 0; mi < 4; ++mi)
#pragma unroll
    for (int ksd = 0; ksd < 2; ++ksd)
      qf[mi][ksd] = *(const bf16x8*)(Qbh + (size_t)(m0 + wm + mi * 16 + r16) * T_DH +
                                     ksd * 32 + quad * 8);

  float rs[4][4];
#pragma unroll
  for (int i = 0; i < 4; ++i)
#pragma unroll
    for (int j = 0; j < 4; ++j) rs[i][j] = 0.f;
  const f32x4 zf = {0.f, 0.f, 0.f, 0.f};
  f32x4 accp[2][4];
#pragma unroll
  for (int i = 0; i < 2; ++i)
#pragma unroll
    for (int j = 0; j < 4; ++j) accp[i][j] = zf;

  for (int kt = 0; kt <= qb; ++kt) {
    f32x4 accs[4][4];
#pragma unroll
    for (int i = 0; i < 4; ++i)
#pragma unroll
      for (int j = 0; j < 4; ++j) accs[i][j] = zf;
#pragma unroll
    for (int ksd = 0; ksd < 2; ++ksd) {
      bf16x8 bv[4];
#pragma unroll
      for (int ni = 0; ni < 4; ++ni)
        bv[ni] = *(const bf16x8*)(Kbh + (size_t)(kt * 128 + wn + ni * 16 + r16) * T_DH +
                                  ksd * 32 + quad * 8);
#pragma unroll
      for (int mi = 0; mi < 4; ++mi)
#pragma unroll
        for (int ni = 0; ni < 4; ++ni)
          accs[mi][ni] = __builtin_amdgcn_mfma_f32_16x16x32_bf16(
              qf[mi][ksd], bv[ni], accs[mi][ni], 0, 0, 0);
    }
    __syncthreads();
    const bool diag = (kt == qb);
#pragma unroll
    for (int mi = 0; mi < 4; ++mi) {
#pragma unroll
      for (int ni = 0; ni < 4; ++ni) {
        const int cbase = wn + ni * 16;
        const int kse = cbase >> 5;
        const int sin = (cbase & 31) + r16;
        short* ep = Es + kse * 4096 + (wm + mi * 16 + quad * 4) * 32 + sin;
        const int colw = cbase + r16;
#pragma unroll
        for (int reg = 0; reg < 4; ++reg) {
          float e = __expf(accs[mi][ni][reg] * 0.125f);
          if (diag && colw > (wm + mi * 16 + quad * 4 + reg)) e = 0.f;
          ep[reg * 32] = f2bf(e);
          rs[mi][reg] += e;
        }
      }
    }
    __syncthreads();
#pragma unroll
    for (int ks = 0; ks < 4; ++ks) {
      bf16x8 av[2], bvv[4];
#pragma unroll
      for (int i = 0; i < 2; ++i)
        av[i] = *(const bf16x8*)(Es + ks * 4096 + (pvm + i * 16 + r16) * 32 + quad * 8);
#pragma unroll
      for (int ni = 0; ni < 4; ++ni)
        bvv[ni] = *(const bf16x8*)(Vbh + (size_t)(ni * 16 + r16) * T_S + kt * 128 +
                                   ks * 32 + quad * 8);
#pragma unroll
      for (int i = 0; i < 2; ++i)
#pragma unroll
        for (int ni = 0; ni < 4; ++ni)
          accp[i][ni] = __builtin_amdgcn_mfma_f32_16x16x32_bf16(av[i], bvv[ni],
                                                                accp[i][ni], 0, 0, 0);
    }
  }

#pragma unroll
  for (int mi = 0; mi < 4; ++mi)
#pragma unroll
    for (int reg = 0; reg < 4; ++reg) {
#pragma unroll
      for (int d = 1; d < 16; d <<= 1)
        rs[mi][reg] += __shfl_xor(rs[mi][reg], d, 64);
    }
  if (r16 == 0) {
#pragma unroll
    for (int mi = 0; mi < 4; ++mi)
#pragma unroll
      for (int reg = 0; reg < 4; ++reg)
        rsbuf[wid & 1][wm + mi * 16 + quad * 4 + reg] = rs[mi][reg];
  }
  __syncthreads();
  if (t < 128) {
    const float iv = 1.f / (rsbuf[0][t] + rsbuf[1][t]);
    rsbuf[0][t] = iv;
    rsinv_g[(size_t)bh * T_S + m0 + t] = iv;
  }
  __syncthreads();
#pragma unroll
  for (int i = 0; i < 2; ++i)
#pragma unroll
    for (int ni = 0; ni < 4; ++ni) {
#pragma unroll
      for (int reg = 0; reg < 4; ++reg) {
        const int row = pvm + i * 16 + quad * 4 + reg;
        const float iv = rsbuf[0][row];
        ctx[((size_t)b * T_S + m0 + row) * T_D + h * 64 + ni * 16 + r16] =
            f2bf(accp[i][ni][reg] * iv);
      }
    }
}

// Pass 2 (unchanged): write attn; masked tiles zero; else recompute scores.
__global__ __launch_bounds__(256) void attn_pass2(
    const short* __restrict__ qg, const short* __restrict__ kg,
    const float* __restrict__ rsinv_g, float* __restrict__ attn) {
  const int qb = blockIdx.x, kt = blockIdx.y, bh = blockIdx.z;
  float* out = attn + ((size_t)bh * T_S + qb * 128) * T_S + kt * 128;
  const int t = threadIdx.x;
  if (kt > qb) {
    const float4 z4 = {0.f, 0.f, 0.f, 0.f};
#pragma unroll
    for (int j = 0; j < 16; ++j) {
      const int id = t + j * 256;
      ((float4*)(out + (size_t)(id >> 5) * T_S))[id & 31] = z4;
    }
    return;
  }
  const int lane = t & 63, wid = t >> 6;
  const int quad = lane >> 4, r16 = lane & 15;
  const int wm = (wid >> 1) << 6, wn = (wid & 1) << 6;
  const short* Qbh = qg + (size_t)bh * T_S * T_DH;
  const short* Kbh = kg + (size_t)bh * T_S * T_DH;
  const f32x4 zf = {0.f, 0.f, 0.f, 0.f};
  f32x4 accs[4][4];
#pragma unroll
  for (int i = 0; i < 4; ++i)
#pragma unroll
    for (int j = 0; j < 4; ++j) accs[i][j] = zf;
#pragma unroll
  for (int ksd = 0; ksd < 2; ++ksd) {
    bf16x8 aq[4], bv[4];
#pragma unroll
    for (int mi = 0; mi < 4; ++mi)
      aq[mi] = *(const bf16x8*)(Qbh + (size_t)(qb * 128 + wm + mi * 16 + r16) * T_DH +
                                ksd * 32 + quad * 8);
#pragma unroll
    for (int ni = 0; ni < 4; ++ni)
      bv[ni] = *(const bf16x8*)(Kbh + (size_t)(kt * 128 + wn + ni * 16 + r16) * T_DH +
                                ksd * 32 + quad * 8);
#pragma unroll
    for (int mi = 0; mi < 4; ++mi)
#pragma unroll
      for (int ni = 0; ni < 4; ++ni)
        accs[mi][ni] = __builtin_amdgcn_mfma_f32_16x16x32_bf16(aq[mi], bv[ni],
                                                               accs[mi][ni], 0, 0, 0);
  }
  const bool diag = (kt == qb);
#pragma unroll
  for (int mi = 0; mi < 4; ++mi)
#pragma unroll
    for (int ni = 0; ni < 4; ++ni) {
      const int col = wn + ni * 16 + r16;
#pragma unroll
      for (int reg = 0; reg < 4; ++reg) {
        const int rowt = wm + mi * 16 + quad * 4 + reg;
        const float iv = rsinv_g[(size_t)bh * T_S + qb * 128 + rowt];
        float e = __expf(accs[mi][ni][reg] * 0.125f) * iv;
        if (diag && col > rowt) e = 0.f;
        out[(size_t)rowt * T_S + col] = e;
      }
    }
}

// LayerNorm(a + sum(parts) + biasvec) * g + be. Residual a from f32 or bf16.
__global__ __launch_bounds__(256) void ln_multi(
    const float* __restrict__ a32, const short* __restrict__ a16,
    const float* __restrict__ parts, int nparts, const float* __restrict__ bias,
    const float* __restrict__ g, const float* __restrict__ be,
    float* __restrict__ outf, short* __restrict__ outb) {
  const int row = blockIdx.x;
  const int t = threadIdx.x;
  float4 x;
  if (a32 != nullptr) {
    x = ((const float4*)(a32 + (size_t)row * T_D))[t];
  } else {
    const short4 s4 = ((const short4*)(a16 + (size_t)row * T_D))[t];
    x.x = bf2f(s4.x); x.y = bf2f(s4.y); x.z = bf2f(s4.z); x.w = bf2f(s4.w);
  }
  const float4 bv = ((const float4*)bias)[t];
  x.x += bv.x; x.y += bv.y; x.z += bv.z; x.w += bv.w;
  for (int p = 0; p < nparts; ++p) {
    const float4 v =
        ((const float4*)(parts + (size_t)p * T_TOK * T_D + (size_t)row * T_D))[t];
    x.x += v.x; x.y += v.y; x.z += v.z; x.w += v.w;
  }
  float sum = x.x + x.y + x.z + x.w;
  float sq = x.x * x.x + x.y * x.y + x.z * x.z + x.w * x.w;
  __shared__ float reds[4], redq[4];
  const int lane = t & 63, wid = t >> 6;
#pragma unroll
  for (int o = 32; o > 0; o >>= 1) {
    sum += __shfl_down(sum, o, 64);
    sq += __shfl_down(sq, o, 64);
  }
  if (lane == 0) { reds[wid] = sum; redq[wid] = sq; }
  __syncthreads();
  sum = reds[0] + reds[1] + reds[2] + reds[3];
  sq = redq[0] + redq[1] + redq[2] + redq[3];
  const float mean = sum * (1.f / T_D);
  const float var = sq * (1.f / T_D) - mean * mean;
  const float rstd = rsqrtf(var + 1e-5f);
  const float4 gg = ((const float4*)g)[t];
  const float4 bb = ((const float4*)be)[t];
  float4 y;
  y.x = (x.x - mean) * rstd * gg.x + bb.x;
  y.y = (x.y - mean) * rstd * gg.y + bb.y;
  y.z = (x.z - mean) * rstd * gg.z + bb.z;
  y.w = (x.w - mean) * rstd * gg.w + bb.w;
  if (outf != nullptr) ((float4*)(outf + (size_t)row * T_D))[t] = y;
  if (outb != nullptr) {
    short4 o4;
    o4.x = f2bf(y.x); o4.y = f2bf(y.y); o4.z = f2bf(y.z); o4.w = f2bf(y.w);
    ((short4*)(outb + (size_t)row * T_D))[t] = o4;
  }
}

// Fused prep: x->bf16 (blocks 0..4095) + five weight conversions into the
// PACKED B layout: for weight W[K][N], panel p = n>>7, k-tile kt = k>>5,
// half h = (n>>6)&1, then [g = (n&63)>>4][c = (k&31)>>3][r = n&15] -> 8
// consecutive k-shorts. Section (4096B) = exactly one GEMM staging load.
__global__ __launch_bounds__(256) void prep_kernel(
    const float* __restrict__ x, short* __restrict__ xb,
    const float* __restrict__ Wq, const float* __restrict__ Wk,
    const float* __restrict__ Wv, const float* __restrict__ Wo,
    const float* __restrict__ W1, const float* __restrict__ W2,
    short* __restrict__ Wqkv_t, short* __restrict__ Wo_t,
    short* __restrict__ W1_t, short* __restrict__ W2_t) {
  int id = blockIdx.x;
  const int t = threadIdx.x;
  if (id < 4096) {
    const int i = id * 256 + t;
    const float4 v = ((const float4*)x)[i];
    short4 o;
    o.x = f2bf(v.x); o.y = f2bf(v.y); o.z = f2bf(v.z); o.w = f2bf(v.w);
    ((short4*)xb)[i] = o;
    return;
  }
  id -= 4096;
  const float* src;
  short* dst;
  int R, C;  // src = W[R=K][C=N]
  if (id < 1024) { src = Wq; dst = Wqkv_t; R = 1024; C = 1024; }
  else if (id < 2048) { id -= 1024; src = Wk; dst = Wqkv_t + 1024 * 1024; R = 1024; C = 1024; }
  else if (id < 3072) { id -= 2048; src = Wv; dst = Wqkv_t + 2 * 1024 * 1024; R = 1024; C = 1024; }
  else if (id < 4096) { id -= 3072; src = Wo; dst = Wo_t; R = 1024; C = 1024; }
  else if (id < 8192) { id -= 4096; src = W1; dst = W1_t; R = 1024; C = 4096; }
  else { id -= 8192; src = W2; dst = W2_t; R = 4096; C = 1024; }
  const int tilesC = C >> 5;
  const int r0 = (id / tilesC) << 5, c0 = (id % tilesC) << 5;  // k0, n0
  __shared__ float tile[32][33];
  const int tx = t & 31, ty = t >> 5;  // 32 x 8
#pragma unroll
  for (int j = 0; j < 4; ++j)
    tile[ty + j * 8][tx] = src[(size_t)(r0 + ty + j * 8) * C + c0 + tx];
  __syncthreads();
  // packed emit: 128 chunks of 16B; thread t<128 handles (b = n-in-32,
  // c = k-chunk): chunk = W[r0 + c*8 + j][c0 + b] = tile[c*8+j][b].
  if (t < 128) {
    const int b = t >> 2, c = t & 3;
    bf16x8 v8;
#pragma unroll
    for (int j = 0; j < 8; ++j) v8[j] = f2bf(tile[c * 8 + j][b]);
    const int p = c0 >> 7, h = (c0 >> 6) & 1;
    const int g = ((c0 & 63) >> 4) + (b >> 4), r = b & 15;
    char* dp = (char*)dst + ((size_t)p * (R >> 5) + (r0 >> 5)) * 8192 +
               h * 4096 + g * 1024 + c * 256 + r * 16;
    *(bf16x8*)dp = v8;
  }
}

extern "C" void kernel_launch(void* const* d_in, const int* in_sizes, int n_in,
                              void* d_out, int out_size, void* d_ws,
                              size_t ws_size, hipStream_t stream) {
  const float* x = (const float*)d_in[0];
  const float* Wq = (const float*)d_in[1];
  const float* bq = (const float*)d_in[2];
  const float* Wk = (const float*)d_in[3];
  const float* bk = (const float*)d_in[4];
  const float* Wv = (const float*)d_in[5];
  const float* bv = (const float*)d_in[6];
  const float* Wo = (const float*)d_in[7];
  const float* bo = (const float*)d_in[8];
  const float* ln1g = (const float*)d_in[9];
  const float* ln1b = (const float*)d_in[10];
  const float* W1 = (const float*)d_in[11];
  const float* b1 = (const float*)d_in[12];
  const float* W2 = (const float*)d_in[13];
  const float* b2 = (const float*)d_in[14];
  const float* ln2g = (const float*)d_in[15];
  const float* ln2b = (const float*)d_in[16];
  (void)in_sizes; (void)n_in; (void)out_size; (void)ws_size;

  float* y_out = (float*)d_out;
  float* attn = (float*)d_out + (size_t)T_TOK * T_D;

  char* w = (char*)d_ws;
  size_t off = 0;
  auto alloc = [&](size_t bytes) -> void* {
    void* p = w + off;
    off += (bytes + 255) & ~(size_t)255;
    return p;
  };
  short* xb     = (short*)alloc((size_t)T_TOK * T_D * 2);
  short* Wqkv_t = (short*)alloc((size_t)3 * T_D * T_D * 2);
  short* Wo_t   = (short*)alloc((size_t)T_D * T_D * 2);
  short* W1_t   = (short*)alloc((size_t)T_FF * T_D * 2);
  short* W2_t   = (short*)alloc((size_t)T_D * T_FF * 2);
  short* qb_    = (short*)alloc((size_t)T_TOK * T_D * 2);
  short* kb_    = (short*)alloc((size_t)T_TOK * T_D * 2);
  short* vtb    = (short*)alloc((size_t)T_TOK * T_D * 2);
  short* ctx    = (short*)alloc((size_t)T_TOK * T_D * 2);
  short* hb     = (short*)alloc((size_t)T_TOK * T_D * 2);
  short* ff1    = (short*)alloc((size_t)T_TOK * T_FF * 2);
  float* rsinv  = (float*)alloc((size_t)T_H * T_B * T_S * 4);
  float* woP    = (float*)alloc((size_t)2 * T_TOK * T_D * 4);
  float* ffP    = (float*)alloc((size_t)2 * T_TOK * T_D * 4);

  prep_kernel<<<dim3(16384), dim3(256), 0, stream>>>(
      x, xb, Wq, Wk, Wv, Wo, W1, W2, Wqkv_t, Wo_t, W1_t, W2_t);

  gemm_dense<0><<<dim3(32, 24), dim3(256), 0, stream>>>(
      xb, Wqkv_t, T_D, 3072, bq, bk, bv, qb_, kb_, vtb);
  attn_pass1<<<dim3(8, 64), dim3(256), 0, stream>>>(qb_, kb_, vtb, ctx, rsinv);
  attn_pass2<<<dim3(8, 8, 64), dim3(256), 0, stream>>>(qb_, kb_, rsinv, attn);

  gemm_splitk<<<dim3(32, 8, 2), dim3(256), 0, stream>>>(ctx, Wo_t, T_D, T_D, 512, woP);
  ln_multi<<<dim3(4096), dim3(256), 0, stream>>>(x, nullptr, woP, 2, bo, ln1g,
                                                 ln1b, nullptr, hb);

  gemm_dense<2><<<dim3(32, 32), dim3(256), 0, stream>>>(
      hb, W1_t, T_D, T_FF, b1, nullptr, nullptr, ff1, nullptr, nullptr);
  gemm_splitk<<<dim3(32, 8, 2), dim3(256), 0, stream>>>(ff1, W2_t, T_FF, T_D, 2048, ffP);
  ln_multi<<<dim3(4096), dim3(256), 0, stream>>>(nullptr, hb, ffP, 2, b2, ln2g,
                                                 ln2b, y_out, nullptr);
}

// Round 5
// 608.966 us; speedup vs baseline: 1.1180x; 1.0128x over previous
//
#include <hip/hip_runtime.h>
#include <cstdint>

// Transformer decoder layer, MI355X gfx950. B=4 S=1024 D=1024 H=16 DH=64 FF=4096.
// Round 8: overlap BW-bound attn_pass2 with compute-bound FF2 split-K by
// merging their grids into ONE kernel launch (block-uniform branch on
// blockIdx.x; no shared state; disjoint outputs). attn_pass2 depends only on
// pass1 outputs (qb_, kb_, rsinv) and nothing reads attn downstream, so the
// move is dependency-safe. GEMM ring mainloop + packed-B unchanged from
// round 7 (616.8 us).

#define T_B 4
#define T_S 1024
#define T_D 1024
#define T_H 16
#define T_DH 64
#define T_FF 4096
#define T_TOK (T_B * T_S)

typedef __attribute__((ext_vector_type(8))) short bf16x8;
typedef __attribute__((ext_vector_type(4))) float f32x4;

__device__ __forceinline__ short f2bf(float f) {
  uint32_t u = __float_as_uint(f);
  u += 0x7FFFu + ((u >> 16) & 1u);  // round-to-nearest-even
  return (short)(u >> 16);
}

__device__ __forceinline__ float bf2f(short s) {
  return __uint_as_float(((uint32_t)(unsigned short)s) << 16);
}

// async global->LDS, 16B per lane. LDS dest = wave-uniform base + lane*16.
__device__ __forceinline__ void async_copy16(void* lds, const void* g) {
  __builtin_amdgcn_global_load_lds(
      (__attribute__((address_space(1))) uint32_t*)(uintptr_t)g,
      (__attribute__((address_space(3))) uint32_t*)(uint32_t)(uintptr_t)lds,
      16, 0, 0);
}

// Stage one 128x32 A-tile (row-major source, 16x64B runs) + one 128x32
// packed-B tile (two 4096B contiguous sections) into ring slot `base`.
// Slot: A rows 0-63 at +0, A rows 64-127 at +4096, B n0-63 at +8192,
// B n64-127 at +12288. 4 loads/thread.
__device__ __forceinline__ void stage_ring(char* base, const char* gA0,
                                           const char* gA1, const char* gB0,
                                           const char* gB1, int koffA, int koffB,
                                           int wid) {
  async_copy16(base + (wid << 10), gA0 + koffA);
  async_copy16(base + 4096 + (wid << 10), gA1 + koffA);
  async_copy16(base + 8192 + (wid << 10), gB0 + koffB);
  async_copy16(base + 12288 + (wid << 10), gB1 + koffB);
}

// A fragments: proven row-major reads. B fragments: packed layout ->
// slot + 8192 + (wn>>6)*4096 + i*1024 + lane*16 (64 lanes x 16B contiguous).
__device__ __forceinline__ void compute32(const char* slot, int wm, int quad,
                                          int r16, int boffB, f32x4 acc[4][4]) {
  const short* As = (const short*)slot;
  bf16x8 av[4], bv[4];
#pragma unroll
  for (int i = 0; i < 4; ++i) {
    av[i] = *(const bf16x8*)(As + ((wm + i * 16 + r16) << 5) + (quad << 3));
    bv[i] = *(const bf16x8*)(slot + 8192 + boffB + (i << 10));
  }
#pragma unroll
  for (int mi = 0; mi < 4; ++mi)
#pragma unroll
    for (int ni = 0; ni < 4; ++ni)
      acc[mi][ni] = __builtin_amdgcn_mfma_f32_16x16x32_bf16(av[mi], bv[ni],
                                                            acc[mi][ni], 0, 0, 0);
}

// 128x128 tile mainloop: 3-buffer ring, BK=32 per iter, counted vmcnt.
// Invariants (proven rounds 4-7):
//  - stage(t+2) issued after the barrier ending iter t-1 (its buffer's
//    readers are done).
//  - vmcnt(4) at end of iter t -> tile t+1 fully landed before the barrier.
//  - tail iters use vmcnt(0).
// A: row-major [M][lda], k-window [0,kLen) (caller pre-offsets for splitk).
// Bpack: packed weights, full-K = ldbK, k-window [kBase, kBase+kLen).
__device__ __forceinline__ void mfma_loop_ring(
    const short* __restrict__ A, int lda, const char* __restrict__ Bpack,
    int ldbK, int kBase, int kLen, int m0, int n0, char* smem,
    f32x4 acc[4][4]) {
  const int t = threadIdx.x;
  const int lane = t & 63, wid = t >> 6;
  const int wm = (wid >> 1) << 6, wn = (wid & 1) << 6;
  const int quad = lane >> 4, r16 = lane & 15;
  const int boffB = ((wn >> 6) << 12) + (lane << 4);
  const int row0 = t >> 2, cb0 = (t & 3) << 4;
  const char* gA0 = (const char*)A + (((size_t)(m0 + row0) * lda) << 1) + cb0;
  const char* gA1 = gA0 + ((size_t)lda << 7);  // +64 rows * 2B
  const char* gB0 = Bpack +
      ((size_t)(n0 >> 7) * (ldbK >> 5) + (kBase >> 5)) * 8192 + (t << 4);
  const char* gB1 = gB0 + 4096;

  const f32x4 zf = {0.f, 0.f, 0.f, 0.f};
#pragma unroll
  for (int i = 0; i < 4; ++i)
#pragma unroll
    for (int j = 0; j < 4; ++j) acc[i][j] = zf;

  const int nIter = kLen >> 5;
  // prologue: stage tiles 0 and 1; wait tile 0 landed (4 of 8 outstanding).
  stage_ring(smem, gA0, gA1, gB0, gB1, 0, 0, wid);
  stage_ring(smem + 16384, gA0, gA1, gB0, gB1, 64, 8192, wid);
  asm volatile("s_waitcnt vmcnt(4)" ::: "memory");
  __builtin_amdgcn_s_barrier();
  __builtin_amdgcn_sched_barrier(0);

  int cur = 0;
  for (int it = 0; it < nIter; ++it) {
    const int k2 = (it + 2) << 5;
    if (k2 < kLen) {
      int nb = cur + 2;
      if (nb >= 3) nb -= 3;
      stage_ring(smem + nb * 16384, gA0, gA1, gB0, gB1, k2 << 1, k2 << 8, wid);
    }
    compute32(smem + cur * 16384, wm, quad, r16, boffB, acc);
    if (k2 < kLen)
      asm volatile("s_waitcnt vmcnt(4)" ::: "memory");
    else
      asm volatile("s_waitcnt vmcnt(0)" ::: "memory");
    __builtin_amdgcn_s_barrier();
    __builtin_amdgcn_sched_barrier(0);
    ++cur;
    if (cur >= 3) cur -= 3;
  }
}

// split-K epilogue + body as device functions (shared by standalone + fused).
__device__ __forceinline__ void splitk_body(int m0, int n0, int z,
                                            const short* __restrict__ A,
                                            const short* __restrict__ Bw, int K,
                                            int N, int kc,
                                            float* __restrict__ outp,
                                            char* smem) {
  f32x4 acc[4][4];
  mfma_loop_ring(A + (size_t)z * kc, K, (const char*)Bw, K, z * kc, kc, m0, n0,
                 smem, acc);
  float* o = outp + (size_t)z * T_TOK * N;
  const int t = threadIdx.x;
  const int lane = t & 63, wid = t >> 6;
  const int wm = (wid >> 1) << 6, wn = (wid & 1) << 6;
  const int quad = lane >> 4, r16 = lane & 15;
#pragma unroll
  for (int mi = 0; mi < 4; ++mi)
#pragma unroll
    for (int ni = 0; ni < 4; ++ni) {
      const int col = n0 + wn + ni * 16 + r16;
#pragma unroll
      for (int reg = 0; reg < 4; ++reg) {
        const int row = m0 + wm + mi * 16 + quad * 4 + reg;
        o[(size_t)row * N + col] = acc[mi][ni][reg];
      }
    }
}

// attn pass-2 body: write attn tile (qb,kt,bh); masked tiles zero; else
// recompute scores and scale by rsinv.
__device__ __forceinline__ void pass2_body(int qb, int kt, int bh,
                                           const short* __restrict__ qg,
                                           const short* __restrict__ kg,
                                           const float* __restrict__ rsinv_g,
                                           float* __restrict__ attn) {
  float* out = attn + ((size_t)bh * T_S + qb * 128) * T_S + kt * 128;
  const int t = threadIdx.x;
  if (kt > qb) {
    const float4 z4 = {0.f, 0.f, 0.f, 0.f};
#pragma unroll
    for (int j = 0; j < 16; ++j) {
      const int id = t + j * 256;
      ((float4*)(out + (size_t)(id >> 5) * T_S))[id & 31] = z4;
    }
    return;
  }
  const int lane = t & 63, wid = t >> 6;
  const int quad = lane >> 4, r16 = lane & 15;
  const int wm = (wid >> 1) << 6, wn = (wid & 1) << 6;
  const short* Qbh = qg + (size_t)bh * T_S * T_DH;
  const short* Kbh = kg + (size_t)bh * T_S * T_DH;
  const f32x4 zf = {0.f, 0.f, 0.f, 0.f};
  f32x4 accs[4][4];
#pragma unroll
  for (int i = 0; i < 4; ++i)
#pragma unroll
    for (int j = 0; j < 4; ++j) accs[i][j] = zf;
#pragma unroll
  for (int ksd = 0; ksd < 2; ++ksd) {
    bf16x8 aq[4], bv[4];
#pragma unroll
    for (int mi = 0; mi < 4; ++mi)
      aq[mi] = *(const bf16x8*)(Qbh + (size_t)(qb * 128 + wm + mi * 16 + r16) * T_DH +
                                ksd * 32 + quad * 8);
#pragma unroll
    for (int ni = 0; ni < 4; ++ni)
      bv[ni] = *(const bf16x8*)(Kbh + (size_t)(kt * 128 + wn + ni * 16 + r16) * T_DH +
                                ksd * 32 + quad * 8);
#pragma unroll
    for (int mi = 0; mi < 4; ++mi)
#pragma unroll
      for (int ni = 0; ni < 4; ++ni)
        accs[mi][ni] = __builtin_amdgcn_mfma_f32_16x16x32_bf16(aq[mi], bv[ni],
                                                               accs[mi][ni], 0, 0, 0);
  }
  const bool diag = (kt == qb);
#pragma unroll
  for (int mi = 0; mi < 4; ++mi)
#pragma unroll
    for (int ni = 0; ni < 4; ++ni) {
      const int col = wn + ni * 16 + r16;
#pragma unroll
      for (int reg = 0; reg < 4; ++reg) {
        const int rowt = wm + mi * 16 + quad * 4 + reg;
        const float iv = rsinv_g[(size_t)bh * T_S + qb * 128 + rowt];
        float e = __expf(accs[mi][ni][reg] * 0.125f) * iv;
        if (diag && col > rowt) e = 0.f;
        out[(size_t)rowt * T_S + col] = e;
      }
    }
}

// MODE 0: QKV fused (N=3072): q[b,h,s,dh], k[b,h,s,dh] direct; vt[b,h,dh,s]
//         staged via LDS for coalesced stores.
// MODE 2: relu bf16 out + bias (FF1)
template <int MODE>
__global__ __launch_bounds__(256) void gemm_dense(
    const short* __restrict__ A, const short* __restrict__ Bw, int K, int N,
    const float* __restrict__ bias0, const float* __restrict__ bias1,
    const float* __restrict__ bias2, short* __restrict__ outb0,
    short* __restrict__ outb1, short* __restrict__ outb2) {
  __shared__ __align__(16) char smem[49152];  // 3 ring buffers of 16 KiB
  const int m0 = blockIdx.x << 7, n0 = blockIdx.y << 7;
  f32x4 acc[4][4];
  mfma_loop_ring(A, K, (const char*)Bw, K, 0, K, m0, n0, smem, acc);

  const int t = threadIdx.x;
  const int lane = t & 63, wid = t >> 6;
  const int wm = (wid >> 1) << 6, wn = (wid & 1) << 6;
  const int quad = lane >> 4, r16 = lane & 15;

  if constexpr (MODE == 0) {
    const int which = n0 >> 10;  // block-uniform: 0=q 1=k 2=v
    const float* bias = (which == 0) ? bias0 : (which == 1) ? bias1 : bias2;
    if (which < 2) {
      short* outp = (which == 0) ? outb0 : outb1;
#pragma unroll
      for (int mi = 0; mi < 4; ++mi) {
#pragma unroll
        for (int ni = 0; ni < 4; ++ni) {
          const int col = n0 + wn + ni * 16 + r16;
          const int c10 = col & 1023;
          const float bb = bias[c10];
          const int hh = c10 >> 6, dh = col & 63;
#pragma unroll
          for (int reg = 0; reg < 4; ++reg) {
            const int row = m0 + wm + mi * 16 + quad * 4 + reg;
            const int b = row >> 10, s = row & 1023;
            outp[((((size_t)b * T_H + hh) * T_S) + s) * T_DH + dh] =
                f2bf(acc[mi][ni][reg] + bb);
          }
        }
      }
    } else {
      // V: stage [col][row] into padded LDS, then coalesced stores along s.
      __syncthreads();  // all waves done reading ring buffers
      short* vtile = (short*)smem;  // 128 x 136
#pragma unroll
      for (int mi = 0; mi < 4; ++mi)
#pragma unroll
        for (int ni = 0; ni < 4; ++ni) {
          const int c = wn + ni * 16 + r16;
          const float bb = bias[(n0 + c) & 1023];
#pragma unroll
          for (int reg = 0; reg < 4; ++reg) {
            const int r = wm + mi * 16 + quad * 4 + reg;
            vtile[c * 136 + r] = f2bf(acc[mi][ni][reg] + bb);
          }
        }
      __syncthreads();
      const int b = m0 >> 10, s0 = m0 & 1023;
      const int c = t >> 1, half = t & 1;
      const int c10 = (n0 + c) & 1023;
      const int hh = c10 >> 6, dh = c10 & 63;
      short* dst = outb2 + (((size_t)b * T_H + hh) * T_DH + dh) * T_S + s0 + half * 64;
      const short* srcl = vtile + c * 136 + half * 64;
#pragma unroll
      for (int j = 0; j < 8; ++j)
        *(bf16x8*)(dst + j * 8) = *(const bf16x8*)(srcl + j * 8);
    }
  } else {
#pragma unroll
    for (int mi = 0; mi < 4; ++mi)
#pragma unroll
      for (int ni = 0; ni < 4; ++ni) {
        const int col = n0 + wn + ni * 16 + r16;
        const float bb = bias0[col];
#pragma unroll
        for (int reg = 0; reg < 4; ++reg) {
          const int row = m0 + wm + mi * 16 + quad * 4 + reg;
          outb0[(size_t)row * N + col] = f2bf(fmaxf(acc[mi][ni][reg] + bb, 0.f));
        }
      }
  }
}

// standalone split-K GEMM (Wo): grid (32, 8, 2).
__global__ __launch_bounds__(256) void gemm_splitk(
    const short* __restrict__ A, const short* __restrict__ Bw, int K, int N,
    int kc, float* __restrict__ outp) {
  __shared__ __align__(16) char smem[49152];
  splitk_body(blockIdx.x << 7, blockIdx.y << 7, blockIdx.z, A, Bw, K, N, kc,
              outp, smem);
}

// Fused FF2 split-K + attn pass-2. Grid: 512 GEMM blocks then 4096 pass2
// blocks. Block-uniform branch; no shared state between the two parts.
__global__ __launch_bounds__(256) void ff2_attn_fused(
    const short* __restrict__ A, const short* __restrict__ Bw, int K, int N,
    int kc, float* __restrict__ outp, const short* __restrict__ qg,
    const short* __restrict__ kg, const float* __restrict__ rsinv_g,
    float* __restrict__ attn) {
  __shared__ __align__(16) char smem[49152];
  const int bx = blockIdx.x;
  if (bx < 512) {
    splitk_body((bx & 31) << 7, ((bx >> 5) & 7) << 7, bx >> 8, A, Bw, K, N, kc,
                outp, smem);
  } else {
    const int id = bx - 512;  // 0..4095
    pass2_body(id & 7, (id >> 3) & 7, id >> 6, qg, kg, rsinv_g, attn);
  }
}

// Flash-style pass 1 (unchanged — verified).
__global__ __launch_bounds__(256) void attn_pass1(
    const short* __restrict__ qg, const short* __restrict__ kg,
    const short* __restrict__ vg, short* __restrict__ ctx,
    float* __restrict__ rsinv_g) {
  const int qb = blockIdx.x;
  const int bh = blockIdx.y;
  const int b = bh >> 4, h = bh & 15;
  const int m0 = qb << 7;
  __shared__ __align__(16) short Es[4 * 128 * 32];
  __shared__ float rsbuf[2][128];
  const int t = threadIdx.x;
  const int lane = t & 63, wid = t >> 6;
  const int quad = lane >> 4, r16 = lane & 15;
  const int wm = (wid >> 1) << 6, wn = (wid & 1) << 6;
  const int pvm = wid << 5;

  const short* Qbh = qg + (size_t)bh * T_S * T_DH;
  const short* Kbh = kg + (size_t)bh * T_S * T_DH;
  const short* Vbh = vg + (size_t)bh * T_DH * T_S;

  bf16x8 qf[4][2];
#pragma unroll
  for (int mi = 0; mi < 4; ++mi)
#pragma unroll
    for (int ksd = 0; ksd < 2; ++ksd)
      qf[mi][ksd] = *(const bf16x8*)(Qbh + (size_t)(m0 + wm + mi * 16 + r16) * T_DH +
                                     ksd * 32 + quad * 8);

  float rs[4][4];
#pragma unroll
  for (int i = 0; i < 4; ++i)
#pragma unroll
    for (int j = 0; j < 4; ++j) rs[i][j] = 0.f;
  const f32x4 zf = {0.f, 0.f, 0.f, 0.f};
  f32x4 accp[2][4];
#pragma unroll
  for (int i = 0; i < 2; ++i)
#pragma unroll
    for (int j = 0; j < 4; ++j) accp[i][j] = zf;

  for (int kt = 0; kt <= qb; ++kt) {
    f32x4 accs[4][4];
#pragma unroll
    for (int i = 0; i < 4; ++i)
#pragma unroll
      for (int j = 0; j < 4; ++j) accs[i][j] = zf;
#pragma unroll
    for (int ksd = 0; ksd < 2; ++ksd) {
      bf16x8 bv[4];
#pragma unroll
      for (int ni = 0; ni < 4; ++ni)
        bv[ni] = *(const bf16x8*)(Kbh + (size_t)(kt * 128 + wn + ni * 16 + r16) * T_DH +
                                  ksd * 32 + quad * 8);
#pragma unroll
      for (int mi = 0; mi < 4; ++mi)
#pragma unroll
        for (int ni = 0; ni < 4; ++ni)
          accs[mi][ni] = __builtin_amdgcn_mfma_f32_16x16x32_bf16(
              qf[mi][ksd], bv[ni], accs[mi][ni], 0, 0, 0);
    }
    __syncthreads();
    const bool diag = (kt == qb);
#pragma unroll
    for (int mi = 0; mi < 4; ++mi) {
#pragma unroll
      for (int ni = 0; ni < 4; ++ni) {
        const int cbase = wn + ni * 16;
        const int kse = cbase >> 5;
        const int sin = (cbase & 31) + r16;
        short* ep = Es + kse * 4096 + (wm + mi * 16 + quad * 4) * 32 + sin;
        const int colw = cbase + r16;
#pragma unroll
        for (int reg = 0; reg < 4; ++reg) {
          float e = __expf(accs[mi][ni][reg] * 0.125f);
          if (diag && colw > (wm + mi * 16 + quad * 4 + reg)) e = 0.f;
          ep[reg * 32] = f2bf(e);
          rs[mi][reg] += e;
        }
      }
    }
    __syncthreads();
#pragma unroll
    for (int ks = 0; ks < 4; ++ks) {
      bf16x8 av[2], bvv[4];
#pragma unroll
      for (int i = 0; i < 2; ++i)
        av[i] = *(const bf16x8*)(Es + ks * 4096 + (pvm + i * 16 + r16) * 32 + quad * 8);
#pragma unroll
      for (int ni = 0; ni < 4; ++ni)
        bvv[ni] = *(const bf16x8*)(Vbh + (size_t)(ni * 16 + r16) * T_S + kt * 128 +
                                   ks * 32 + quad * 8);
#pragma unroll
      for (int i = 0; i < 2; ++i)
#pragma unroll
        for (int ni = 0; ni < 4; ++ni)
          accp[i][ni] = __builtin_amdgcn_mfma_f32_16x16x32_bf16(av[i], bvv[ni],
                                                                accp[i][ni], 0, 0, 0);
    }
  }

#pragma unroll
  for (int mi = 0; mi < 4; ++mi)
#pragma unroll
    for (int reg = 0; reg < 4; ++reg) {
#pragma unroll
      for (int d = 1; d < 16; d <<= 1)
        rs[mi][reg] += __shfl_xor(rs[mi][reg], d, 64);
    }
  if (r16 == 0) {
#pragma unroll
    for (int mi = 0; mi < 4; ++mi)
#pragma unroll
      for (int reg = 0; reg < 4; ++reg)
        rsbuf[wid & 1][wm + mi * 16 + quad * 4 + reg] = rs[mi][reg];
  }
  __syncthreads();
  if (t < 128) {
    const float iv = 1.f / (rsbuf[0][t] + rsbuf[1][t]);
    rsbuf[0][t] = iv;
    rsinv_g[(size_t)bh * T_S + m0 + t] = iv;
  }
  __syncthreads();
#pragma unroll
  for (int i = 0; i < 2; ++i)
#pragma unroll
    for (int ni = 0; ni < 4; ++ni) {
#pragma unroll
      for (int reg = 0; reg < 4; ++reg) {
        const int row = pvm + i * 16 + quad * 4 + reg;
        const float iv = rsbuf[0][row];
        ctx[((size_t)b * T_S + m0 + row) * T_D + h * 64 + ni * 16 + r16] =
            f2bf(accp[i][ni][reg] * iv);
      }
    }
}

// LayerNorm(a + sum(parts) + biasvec) * g + be. Residual a from f32 or bf16.
__global__ __launch_bounds__(256) void ln_multi(
    const float* __restrict__ a32, const short* __restrict__ a16,
    const float* __restrict__ parts, int nparts, const float* __restrict__ bias,
    const float* __restrict__ g, const float* __restrict__ be,
    float* __restrict__ outf, short* __restrict__ outb) {
  const int row = blockIdx.x;
  const int t = threadIdx.x;
  float4 x;
  if (a32 != nullptr) {
    x = ((const float4*)(a32 + (size_t)row * T_D))[t];
  } else {
    const short4 s4 = ((const short4*)(a16 + (size_t)row * T_D))[t];
    x.x = bf2f(s4.x); x.y = bf2f(s4.y); x.z = bf2f(s4.z); x.w = bf2f(s4.w);
  }
  const float4 bv = ((const float4*)bias)[t];
  x.x += bv.x; x.y += bv.y; x.z += bv.z; x.w += bv.w;
  for (int p = 0; p < nparts; ++p) {
    const float4 v =
        ((const float4*)(parts + (size_t)p * T_TOK * T_D + (size_t)row * T_D))[t];
    x.x += v.x; x.y += v.y; x.z += v.z; x.w += v.w;
  }
  float sum = x.x + x.y + x.z + x.w;
  float sq = x.x * x.x + x.y * x.y + x.z * x.z + x.w * x.w;
  __shared__ float reds[4], redq[4];
  const int lane = t & 63, wid = t >> 6;
#pragma unroll
  for (int o = 32; o > 0; o >>= 1) {
    sum += __shfl_down(sum, o, 64);
    sq += __shfl_down(sq, o, 64);
  }
  if (lane == 0) { reds[wid] = sum; redq[wid] = sq; }
  __syncthreads();
  sum = reds[0] + reds[1] + reds[2] + reds[3];
  sq = redq[0] + redq[1] + redq[2] + redq[3];
  const float mean = sum * (1.f / T_D);
  const float var = sq * (1.f / T_D) - mean * mean;
  const float rstd = rsqrtf(var + 1e-5f);
  const float4 gg = ((const float4*)g)[t];
  const float4 bb = ((const float4*)be)[t];
  float4 y;
  y.x = (x.x - mean) * rstd * gg.x + bb.x;
  y.y = (x.y - mean) * rstd * gg.y + bb.y;
  y.z = (x.z - mean) * rstd * gg.z + bb.z;
  y.w = (x.w - mean) * rstd * gg.w + bb.w;
  if (outf != nullptr) ((float4*)(outf + (size_t)row * T_D))[t] = y;
  if (outb != nullptr) {
    short4 o4;
    o4.x = f2bf(y.x); o4.y = f2bf(y.y); o4.z = f2bf(y.z); o4.w = f2bf(y.w);
    ((short4*)(outb + (size_t)row * T_D))[t] = o4;
  }
}

// Fused prep: x->bf16 (blocks 0..4095) + five weight conversions into the
// PACKED B layout: for weight W[K][N], panel p = n>>7, k-tile kt = k>>5,
// half h = (n>>6)&1, then [g][c][r] -> 8 consecutive k-shorts. Section
// (4096B) = exactly one GEMM staging load.
__global__ __launch_bounds__(256) void prep_kernel(
    const float* __restrict__ x, short* __restrict__ xb,
    const float* __restrict__ Wq, const float* __restrict__ Wk,
    const float* __restrict__ Wv, const float* __restrict__ Wo,
    const float* __restrict__ W1, const float* __restrict__ W2,
    short* __restrict__ Wqkv_t, short* __restrict__ Wo_t,
    short* __restrict__ W1_t, short* __restrict__ W2_t) {
  int id = blockIdx.x;
  const int t = threadIdx.x;
  if (id < 4096) {
    const int i = id * 256 + t;
    const float4 v = ((const float4*)x)[i];
    short4 o;
    o.x = f2bf(v.x); o.y = f2bf(v.y); o.z = f2bf(v.z); o.w = f2bf(v.w);
    ((short4*)xb)[i] = o;
    return;
  }
  id -= 4096;
  const float* src;
  short* dst;
  int R, C;  // src = W[R=K][C=N]
  if (id < 1024) { src = Wq; dst = Wqkv_t; R = 1024; C = 1024; }
  else if (id < 2048) { id -= 1024; src = Wk; dst = Wqkv_t + 1024 * 1024; R = 1024; C = 1024; }
  else if (id < 3072) { id -= 2048; src = Wv; dst = Wqkv_t + 2 * 1024 * 1024; R = 1024; C = 1024; }
  else if (id < 4096) { id -= 3072; src = Wo; dst = Wo_t; R = 1024; C = 1024; }
  else if (id < 8192) { id -= 4096; src = W1; dst = W1_t; R = 1024; C = 4096; }
  else { id -= 8192; src = W2; dst = W2_t; R = 4096; C = 1024; }
  const int tilesC = C >> 5;
  const int r0 = (id / tilesC) << 5, c0 = (id % tilesC) << 5;  // k0, n0
  __shared__ float tile[32][33];
  const int tx = t & 31, ty = t >> 5;  // 32 x 8
#pragma unroll
  for (int j = 0; j < 4; ++j)
    tile[ty + j * 8][tx] = src[(size_t)(r0 + ty + j * 8) * C + c0 + tx];
  __syncthreads();
  // packed emit: 128 chunks of 16B; thread t<128 handles (b = n-in-32,
  // c = k-chunk): chunk = W[r0 + c*8 + j][c0 + b] = tile[c*8+j][b].
  if (t < 128) {
    const int b = t >> 2, c = t & 3;
    bf16x8 v8;
#pragma unroll
    for (int j = 0; j < 8; ++j) v8[j] = f2bf(tile[c * 8 + j][b]);
    const int p = c0 >> 7, h = (c0 >> 6) & 1;
    const int g = ((c0 & 63) >> 4) + (b >> 4), r = b & 15;
    char* dp = (char*)dst + ((size_t)p * (R >> 5) + (r0 >> 5)) * 8192 +
               h * 4096 + g * 1024 + c * 256 + r * 16;
    *(bf16x8*)dp = v8;
  }
}

extern "C" void kernel_launch(void* const* d_in, const int* in_sizes, int n_in,
                              void* d_out, int out_size, void* d_ws,
                              size_t ws_size, hipStream_t stream) {
  const float* x = (const float*)d_in[0];
  const float* Wq = (const float*)d_in[1];
  const float* bq = (const float*)d_in[2];
  const float* Wk = (const float*)d_in[3];
  const float* bk = (const float*)d_in[4];
  const float* Wv = (const float*)d_in[5];
  const float* bv = (const float*)d_in[6];
  const float* Wo = (const float*)d_in[7];
  const float* bo = (const float*)d_in[8];
  const float* ln1g = (const float*)d_in[9];
  const float* ln1b = (const float*)d_in[10];
  const float* W1 = (const float*)d_in[11];
  const float* b1 = (const float*)d_in[12];
  const float* W2 = (const float*)d_in[13];
  const float* b2 = (const float*)d_in[14];
  const float* ln2g = (const float*)d_in[15];
  const float* ln2b = (const float*)d_in[16];
  (void)in_sizes; (void)n_in; (void)out_size; (void)ws_size;

  float* y_out = (float*)d_out;
  float* attn = (float*)d_out + (size_t)T_TOK * T_D;

  char* w = (char*)d_ws;
  size_t off = 0;
  auto alloc = [&](size_t bytes) -> void* {
    void* p = w + off;
    off += (bytes + 255) & ~(size_t)255;
    return p;
  };
  short* xb     = (short*)alloc((size_t)T_TOK * T_D * 2);
  short* Wqkv_t = (short*)alloc((size_t)3 * T_D * T_D * 2);
  short* Wo_t   = (short*)alloc((size_t)T_D * T_D * 2);
  short* W1_t   = (short*)alloc((size_t)T_FF * T_D * 2);
  short* W2_t   = (short*)alloc((size_t)T_D * T_FF * 2);
  short* qb_    = (short*)alloc((size_t)T_TOK * T_D * 2);
  short* kb_    = (short*)alloc((size_t)T_TOK * T_D * 2);
  short* vtb    = (short*)alloc((size_t)T_TOK * T_D * 2);
  short* ctx    = (short*)alloc((size_t)T_TOK * T_D * 2);
  short* hb     = (short*)alloc((size_t)T_TOK * T_D * 2);
  short* ff1    = (short*)alloc((size_t)T_TOK * T_FF * 2);
  float* rsinv  = (float*)alloc((size_t)T_H * T_B * T_S * 4);
  float* woP    = (float*)alloc((size_t)2 * T_TOK * T_D * 4);
  float* ffP    = (float*)alloc((size_t)2 * T_TOK * T_D * 4);

  prep_kernel<<<dim3(16384), dim3(256), 0, stream>>>(
      x, xb, Wq, Wk, Wv, Wo, W1, W2, Wqkv_t, Wo_t, W1_t, W2_t);

  gemm_dense<0><<<dim3(32, 24), dim3(256), 0, stream>>>(
      xb, Wqkv_t, T_D, 3072, bq, bk, bv, qb_, kb_, vtb);
  attn_pass1<<<dim3(8, 64), dim3(256), 0, stream>>>(qb_, kb_, vtb, ctx, rsinv);

  gemm_splitk<<<dim3(32, 8, 2), dim3(256), 0, stream>>>(ctx, Wo_t, T_D, T_D, 512, woP);
  ln_multi<<<dim3(4096), dim3(256), 0, stream>>>(x, nullptr, woP, 2, bo, ln1g,
                                                 ln1b, nullptr, hb);

  gemm_dense<2><<<dim3(32, 32), dim3(256), 0, stream>>>(
      hb, W1_t, T_D, T_FF, b1, nullptr, nullptr, ff1, nullptr, nullptr);
  // FF2 split-K overlapped with attn pass-2 (independent work) in one launch.
  ff2_attn_fused<<<dim3(4608), dim3(256), 0, stream>>>(
      ff1, W2_t, T_FF, T_D, 2048, ffP, qb_, kb_, rsinv, attn);
  ln_multi<<<dim3(4096), dim3(256), 0, stream>>>(nullptr, hb, ffP, 2, b2, ln2g,
                                                 ln2b, y_out, nullptr);
}